// Round 1
// baseline (7048.360 us; speedup 1.0000x reference)
//
#include <hip/hip_runtime.h>

typedef _Float16 half_t;
typedef _Float16 half2_t __attribute__((ext_vector_type(2)));
typedef _Float16 half4_t __attribute__((ext_vector_type(4)));
typedef _Float16 half8_t __attribute__((ext_vector_type(8)));
typedef float    floatx4 __attribute__((ext_vector_type(4)));

#define T_SEQ 2048
#define EDIM  512

// workspace layout (bytes). total required ~71.4 MB
static constexpr size_t EMB_OFF = 0;                       // 32*2048*512 f16 = 67,108,864
static constexpr size_t Q_OFF   = 67108864;                // 2048*512 f16   =  2,097,152
static constexpr size_t WQ_OFF  = Q_OFF  + 2097152;        // 512*512 f16    =    524,288
static constexpr size_t WK_OFF  = WQ_OFF + 524288;
static constexpr size_t WV_OFF  = WK_OFF + 524288;
static constexpr size_t WO_OFF  = WV_OFF + 524288;
static constexpr size_t TE_OFF  = WO_OFF + 524288;         // 32*512 f16 = 32,768 -> end 71,335,936

__device__ __forceinline__ float fdot2f(half2_t a, half2_t b, float c) {
#if __has_builtin(__builtin_amdgcn_fdot2)
  return __builtin_amdgcn_fdot2(a, b, c, false);
#else
  return c + (float)a[0] * (float)b[0] + (float)a[1] * (float)b[1];
#endif
}
__device__ __forceinline__ half2_t mkh2(float a, float b) {
  half2_t r; r[0] = (half_t)a; r[1] = (half_t)b; return r;
}
__device__ __forceinline__ half2_t h2bc(unsigned u) { return __builtin_bit_cast(half2_t, u); }
__device__ __forceinline__ unsigned h2u(half2_t h)  { return __builtin_bit_cast(unsigned, h); }
__device__ __forceinline__ float sigm(float v)  { return __builtin_amdgcn_rcpf(1.f + __expf(-v)); }
__device__ __forceinline__ float tanhf_(float v){ return __builtin_amdgcn_rcpf(1.f + __expf(-2.f * v)) * 2.f - 1.f; }

// ---------------------------------------------------------------------------
// convert fp32 weight matrices + type_emb to f16 in workspace
// total elems = 4*262144 + 16384 = 1,064,960 ; 4 per thread ; grid 1040*256
__global__ void convert_kernel(const float* __restrict__ wq, const float* __restrict__ wk,
                               const float* __restrict__ wvv, const float* __restrict__ wo,
                               const float* __restrict__ te,
                               half_t* __restrict__ wq16, half_t* __restrict__ wk16,
                               half_t* __restrict__ wv16, half_t* __restrict__ wo16,
                               half_t* __restrict__ te16) {
  int i4 = (blockIdx.x * 256 + threadIdx.x) * 4;
  const float* src; half_t* dst; int off;
  if      (i4 < 262144)     { src = wq;  dst = wq16; off = i4; }
  else if (i4 < 2 * 262144) { src = wk;  dst = wk16; off = i4 - 262144; }
  else if (i4 < 3 * 262144) { src = wvv; dst = wv16; off = i4 - 2 * 262144; }
  else if (i4 < 4 * 262144) { src = wo;  dst = wo16; off = i4 - 3 * 262144; }
  else                      { src = te;  dst = te16; off = i4 - 4 * 262144; }
  float4 v = *(const float4*)(src + off);
  half4_t h; h[0] = (half_t)v.x; h[1] = (half_t)v.y; h[2] = (half_t)v.z; h[3] = (half_t)v.w;
  *(half4_t*)(dst + off) = h;
}

// ---------------------------------------------------------------------------
// LSTM: one (branch, direction) chain per block. 256 threads; thread j owns
// the 4 gate rows (i,f,g,o) of hidden unit j. Weights: dims 0..191 in VGPRs
// (f16), dims 192..255 in LDS ([chunk][thread] transposed, conflict-free).
// h double-buffered in LDS as f16 pairs; 1 barrier per step.
#define REG_CH 24   // uint4 h-chunks (8 dims each) covered by register weights
#define LDS_CH 8    // tail chunks in LDS
#define LSTM_LDS_BYTES (4 * LDS_CH * 256 * 16 + 2 * 32 * 16)  // 131072 + 1024

__global__ __launch_bounds__(256, 1)
void lstm_kernel(const float* __restrict__ x,
                 const float* __restrict__ wih_f, const float* __restrict__ whh_f, const float* __restrict__ b_f,
                 const float* __restrict__ wih_b, const float* __restrict__ whh_b, const float* __restrict__ b_b,
                 half_t* __restrict__ emb) {
  extern __shared__ char smem[];
  uint4* wtail = (uint4*)smem;                          // [4*LDS_CH][256]
  uint4* hbuf  = (uint4*)(smem + 4 * LDS_CH * 256 * 16); // [2][32]

  const int bid = blockIdx.x;
  const int n = bid >> 1, dir = bid & 1;
  const int j = threadIdx.x;
  const float* wih  = dir ? wih_b : wih_f;
  const float* whh  = dir ? whh_b : whh_f;
  const float* bias = dir ? b_b   : b_f;

  half2_t whr[4][96];   // dims 0..191 (96 pairs per row)
  half2_t wir[4][6];
  float   bb[4];

#pragma unroll
  for (int r = 0; r < 4; ++r) {
    const size_t row = (size_t)n * 1024 + r * 256 + j;
    const float4* wp = (const float4*)(whh + row * 256);
#pragma unroll
    for (int c = 0; c < 48; ++c) {           // dims 0..191
      float4 w4 = wp[c];
      whr[r][c * 2]     = mkh2(w4.x, w4.y);
      whr[r][c * 2 + 1] = mkh2(w4.z, w4.w);
    }
#pragma unroll
    for (int c8 = 0; c8 < LDS_CH; ++c8) {    // dims 192..255
      float4 a = wp[48 + c8 * 2], b2 = wp[49 + c8 * 2];
      uint4 u;
      u.x = h2u(mkh2(a.x, a.y));  u.y = h2u(mkh2(a.z, a.w));
      u.z = h2u(mkh2(b2.x, b2.y)); u.w = h2u(mkh2(b2.z, b2.w));
      wtail[(r * LDS_CH + c8) * 256 + j] = u;
    }
    const float* ip = wih + row * 12;
#pragma unroll
    for (int d = 0; d < 6; ++d) wir[r][d] = mkh2(ip[2 * d], ip[2 * d + 1]);
    bb[r] = bias[row];
  }
  if (j < 32) { uint4 z; z.x = z.y = z.z = z.w = 0u; hbuf[j] = z; }  // h_{-1} = 0
  __syncthreads();

  float cst = 0.f;
  int tin0 = dir ? 2047 : 0;
  const float4* xp = (const float4*)(x + ((size_t)n * T_SEQ + tin0) * 12);
  float4 xc0 = xp[0], xc1 = xp[1], xc2 = xp[2];

#pragma unroll 1
  for (int s = 0; s < T_SEQ; ++s) {
    const int tcur = dir ? (2047 - s) : s;
    int tnext = dir ? (2046 - s) : (s + 1);
    if (s == 2047) tnext = tcur;
    const float4* xn = (const float4*)(x + ((size_t)n * T_SEQ + tnext) * 12);
    float4 xb0 = xn[0], xb1 = xn[1], xb2 = xn[2];

    half2_t xh[6] = { mkh2(xc0.x, xc0.y), mkh2(xc0.z, xc0.w),
                      mkh2(xc1.x, xc1.y), mkh2(xc1.z, xc1.w),
                      mkh2(xc2.x, xc2.y), mkh2(xc2.z, xc2.w) };
    float acc0 = bb[0], acc1 = bb[1], acc2 = bb[2], acc3 = bb[3];
#pragma unroll
    for (int d = 0; d < 6; ++d) {
      acc0 = fdot2f(wir[0][d], xh[d], acc0);
      acc1 = fdot2f(wir[1][d], xh[d], acc1);
      acc2 = fdot2f(wir[2][d], xh[d], acc2);
      acc3 = fdot2f(wir[3][d], xh[d], acc3);
    }

    const uint4* hb = hbuf + 32 * (s & 1);
#pragma unroll
    for (int c = 0; c < REG_CH; ++c) {
      uint4 hv = hb[c];
      half2_t h0 = h2bc(hv.x), h1 = h2bc(hv.y), h2 = h2bc(hv.z), h3 = h2bc(hv.w);
      acc0 = fdot2f(whr[0][4 * c + 0], h0, acc0);
      acc0 = fdot2f(whr[0][4 * c + 1], h1, acc0);
      acc0 = fdot2f(whr[0][4 * c + 2], h2, acc0);
      acc0 = fdot2f(whr[0][4 * c + 3], h3, acc0);
      acc1 = fdot2f(whr[1][4 * c + 0], h0, acc1);
      acc1 = fdot2f(whr[1][4 * c + 1], h1, acc1);
      acc1 = fdot2f(whr[1][4 * c + 2], h2, acc1);
      acc1 = fdot2f(whr[1][4 * c + 3], h3, acc1);
      acc2 = fdot2f(whr[2][4 * c + 0], h0, acc2);
      acc2 = fdot2f(whr[2][4 * c + 1], h1, acc2);
      acc2 = fdot2f(whr[2][4 * c + 2], h2, acc2);
      acc2 = fdot2f(whr[2][4 * c + 3], h3, acc2);
      acc3 = fdot2f(whr[3][4 * c + 0], h0, acc3);
      acc3 = fdot2f(whr[3][4 * c + 1], h1, acc3);
      acc3 = fdot2f(whr[3][4 * c + 2], h2, acc3);
      acc3 = fdot2f(whr[3][4 * c + 3], h3, acc3);
    }
#pragma unroll
    for (int c8 = 0; c8 < LDS_CH; ++c8) {
      uint4 hv = hb[REG_CH + c8];
      half2_t h0 = h2bc(hv.x), h1 = h2bc(hv.y), h2 = h2bc(hv.z), h3 = h2bc(hv.w);
      uint4 w0 = wtail[(0 * LDS_CH + c8) * 256 + j];
      acc0 = fdot2f(h2bc(w0.x), h0, acc0);
      acc0 = fdot2f(h2bc(w0.y), h1, acc0);
      acc0 = fdot2f(h2bc(w0.z), h2, acc0);
      acc0 = fdot2f(h2bc(w0.w), h3, acc0);
      uint4 w1 = wtail[(1 * LDS_CH + c8) * 256 + j];
      acc1 = fdot2f(h2bc(w1.x), h0, acc1);
      acc1 = fdot2f(h2bc(w1.y), h1, acc1);
      acc1 = fdot2f(h2bc(w1.z), h2, acc1);
      acc1 = fdot2f(h2bc(w1.w), h3, acc1);
      uint4 w2 = wtail[(2 * LDS_CH + c8) * 256 + j];
      acc2 = fdot2f(h2bc(w2.x), h0, acc2);
      acc2 = fdot2f(h2bc(w2.y), h1, acc2);
      acc2 = fdot2f(h2bc(w2.z), h2, acc2);
      acc2 = fdot2f(h2bc(w2.w), h3, acc2);
      uint4 w3 = wtail[(3 * LDS_CH + c8) * 256 + j];
      acc3 = fdot2f(h2bc(w3.x), h0, acc3);
      acc3 = fdot2f(h2bc(w3.y), h1, acc3);
      acc3 = fdot2f(h2bc(w3.z), h2, acc3);
      acc3 = fdot2f(h2bc(w3.w), h3, acc3);
    }

    float si = sigm(acc0), sf = sigm(acc1), gg = tanhf_(acc2), so = sigm(acc3);
    cst = sf * cst + si * gg;
    float h = so * tanhf_(cst);
    half_t hh = (half_t)h;
    ((half_t*)(hbuf + 32 * ((s + 1) & 1)))[j] = hh;
    emb[((size_t)n * T_SEQ + tcur) * EDIM + dir * 256 + j] = hh;

    xc0 = xb0; xc1 = xb1; xc2 = xb2;
    __syncthreads();
  }
}

// ---------------------------------------------------------------------------
// q projection: q[t] = emb[branch0,t] @ wq^T + bq, stored f16. Blocks of 32 t.
__global__ __launch_bounds__(256, 1)
void qproj_kernel(const half_t* __restrict__ emb, const half_t* __restrict__ wq16,
                  const float* __restrict__ bq, half_t* __restrict__ q_ws) {
  const int t0 = blockIdx.x * 32;
  const int tid = threadIdx.x;
  const int lane = tid & 63, wid = tid >> 6;
  const int col = lane & 15, grp = lane >> 4;

  floatx4 acc[2][8];
#pragma unroll
  for (int nt = 0; nt < 8; ++nt) {
    int eo = wid * 128 + nt * 16 + col;
    float b = bq[eo];
#pragma unroll
    for (int mt = 0; mt < 2; ++mt) { acc[mt][nt][0] = b; acc[mt][nt][1] = b; acc[mt][nt][2] = b; acc[mt][nt][3] = b; }
  }
  for (int kc = 0; kc < 16; ++kc) {
    const int e = kc * 32 + grp * 8;
    half8_t a[2];
#pragma unroll
    for (int mt = 0; mt < 2; ++mt) {
      int trow = t0 + mt * 16 + col;
      a[mt] = *(const half8_t*)(emb + (size_t)trow * EDIM + e);   // branch 0
    }
#pragma unroll
    for (int nt = 0; nt < 8; ++nt) {
      int eo = wid * 128 + nt * 16 + col;
      half8_t bf = *(const half8_t*)(wq16 + (size_t)eo * EDIM + e);
#pragma unroll
      for (int mt = 0; mt < 2; ++mt)
        acc[mt][nt] = __builtin_amdgcn_mfma_f32_16x16x32_f16(a[mt], bf, acc[mt][nt], 0, 0, 0);
    }
  }
#pragma unroll
  for (int mt = 0; mt < 2; ++mt)
#pragma unroll
    for (int nt = 0; nt < 8; ++nt)
#pragma unroll
      for (int r = 0; r < 4; ++r) {
        int trow = t0 + mt * 16 + grp * 4 + r;
        int eo = wid * 128 + nt * 16 + col;
        q_ws[(size_t)trow * EDIM + eo] = (half_t)acc[mt][nt][r];
      }
}

// ---------------------------------------------------------------------------
// fused attention per timestep t: K/V GEMM (MFMA, accs stay in regs),
// scores+softmax via shfl, ctx via shfl, out-projection. 2 KB LDS.
__global__ __launch_bounds__(256, 1)
void attn_kernel(const half_t* __restrict__ emb, const half_t* __restrict__ q_ws,
                 const half_t* __restrict__ wk16, const half_t* __restrict__ wv16,
                 const half_t* __restrict__ wo16, const half_t* __restrict__ te16,
                 const float* __restrict__ bk, const float* __restrict__ bv,
                 const float* __restrict__ bo, float* __restrict__ out) {
  __shared__ float  scores_lds[128];
  __shared__ float  w_lds[128];
  __shared__ half_t ctx_lds[512];

  const int t = blockIdx.x;
  const int tid = threadIdx.x;
  const int lane = tid & 63, wid = tid >> 6;   // wid == head
  const int col = lane & 15, grp = lane >> 4;

  // ---- Phase 1: K,V GEMM ----
  floatx4 kacc[2][8], vacc[2][8];
#pragma unroll
  for (int nt = 0; nt < 8; ++nt) {
    int eo = wid * 128 + nt * 16 + col;
    float kb = bk[eo], vb = bv[eo];
#pragma unroll
    for (int mt = 0; mt < 2; ++mt) {
      kacc[mt][nt][0] = kb; kacc[mt][nt][1] = kb; kacc[mt][nt][2] = kb; kacc[mt][nt][3] = kb;
      vacc[mt][nt][0] = vb; vacc[mt][nt][1] = vb; vacc[mt][nt][2] = vb; vacc[mt][nt][3] = vb;
    }
  }
  for (int kc = 0; kc < 16; ++kc) {
    const int e = kc * 32 + grp * 8;
    half8_t av[2], ak[2];
#pragma unroll
    for (int mt = 0; mt < 2; ++mt) {
      int branch = mt * 16 + col;
      av[mt] = *(const half8_t*)(emb + ((size_t)branch * T_SEQ + t) * EDIM + e);
      half8_t te = *(const half8_t*)(te16 + (size_t)branch * EDIM + e);
      ak[mt] = av[mt] + te;
    }
#pragma unroll
    for (int nt = 0; nt < 8; ++nt) {
      int eo = wid * 128 + nt * 16 + col;
      half8_t bkf = *(const half8_t*)(wk16 + (size_t)eo * EDIM + e);
      half8_t bvf = *(const half8_t*)(wv16 + (size_t)eo * EDIM + e);
#pragma unroll
      for (int mt = 0; mt < 2; ++mt) {
        kacc[mt][nt] = __builtin_amdgcn_mfma_f32_16x16x32_f16(ak[mt], bkf, kacc[mt][nt], 0, 0, 0);
        vacc[mt][nt] = __builtin_amdgcn_mfma_f32_16x16x32_f16(av[mt], bvf, vacc[mt][nt], 0, 0, 0);
      }
    }
  }

  // ---- Phase 2: scores + softmax (per wave = per head) ----
  float spart[8];
#pragma unroll
  for (int i = 0; i < 8; ++i) spart[i] = 0.f;
#pragma unroll
  for (int nt = 0; nt < 8; ++nt) {
    int eo = wid * 128 + nt * 16 + col;
    float qf = (float)q_ws[(size_t)t * EDIM + eo];
#pragma unroll
    for (int mt = 0; mt < 2; ++mt)
#pragma unroll
      for (int r = 0; r < 4; ++r)
        spart[mt * 4 + r] += qf * kacc[mt][nt][r];
  }
#pragma unroll
  for (int i = 0; i < 8; ++i) {
    float v = spart[i];
    v += __shfl_xor(v, 1); v += __shfl_xor(v, 2); v += __shfl_xor(v, 4); v += __shfl_xor(v, 8);
    spart[i] = v;
  }
  const float scale = 0.08838834764831845f;  // 1/sqrt(128)
  if (col == 0) {
#pragma unroll
    for (int mt = 0; mt < 2; ++mt)
#pragma unroll
      for (int r = 0; r < 4; ++r)
        scores_lds[wid * 32 + mt * 16 + grp * 4 + r] = spart[mt * 4 + r] * scale;
  }
  float sc = scores_lds[wid * 32 + (lane & 31)];
  float m = sc;
  m = fmaxf(m, __shfl_xor(m, 1));  m = fmaxf(m, __shfl_xor(m, 2));
  m = fmaxf(m, __shfl_xor(m, 4));  m = fmaxf(m, __shfl_xor(m, 8));
  m = fmaxf(m, __shfl_xor(m, 16));
  float ex = __expf(sc - m);
  float sm = ex;
  sm += __shfl_xor(sm, 1); sm += __shfl_xor(sm, 2); sm += __shfl_xor(sm, 4);
  sm += __shfl_xor(sm, 8); sm += __shfl_xor(sm, 16);
  float wn = ex * __builtin_amdgcn_rcpf(sm);
  if (lane < 32) w_lds[wid * 32 + lane] = wn;

  // ---- Phase 3: ctx from vacc (per wave, in-register) ----
  float wb[8];
#pragma unroll
  for (int mt = 0; mt < 2; ++mt)
#pragma unroll
    for (int r = 0; r < 4; ++r)
      wb[mt * 4 + r] = w_lds[wid * 32 + mt * 16 + grp * 4 + r];
#pragma unroll
  for (int nt = 0; nt < 8; ++nt) {
    float cx = 0.f;
#pragma unroll
    for (int mt = 0; mt < 2; ++mt)
#pragma unroll
      for (int r = 0; r < 4; ++r)
        cx += wb[mt * 4 + r] * vacc[mt][nt][r];
    cx += __shfl_xor(cx, 16);
    cx += __shfl_xor(cx, 32);
    float cxh = __shfl_xor(cx, 1);
    if ((lane < 16) && ((lane & 1) == 0))
      *(half2_t*)(ctx_lds + wid * 128 + nt * 16 + lane) = mkh2(cx, cxh);
  }
  __syncthreads();

  // ---- Phase 4: attn output + out-projection ----
  if (tid < 32) {
    float a = 0.25f * (w_lds[tid] + w_lds[32 + tid] + w_lds[64 + tid] + w_lds[96 + tid]);
    out[1048576 + (size_t)t * 32 + tid] = a;
  }
  const int eo2 = tid * 2;
  float o0 = bo[eo2], o1 = bo[eo2 + 1];
  const uint4* cl = (const uint4*)ctx_lds;
  const half_t* wrow0 = wo16 + (size_t)eo2 * EDIM;
  const half_t* wrow1 = wrow0 + EDIM;
#pragma unroll 8
  for (int c = 0; c < 64; ++c) {
    uint4 cv = cl[c];
    uint4 w0 = *(const uint4*)(wrow0 + c * 8);
    uint4 w1 = *(const uint4*)(wrow1 + c * 8);
    half2_t c0 = h2bc(cv.x), c1 = h2bc(cv.y), c2 = h2bc(cv.z), c3 = h2bc(cv.w);
    o0 = fdot2f(h2bc(w0.x), c0, o0);
    o0 = fdot2f(h2bc(w0.y), c1, o0);
    o0 = fdot2f(h2bc(w0.z), c2, o0);
    o0 = fdot2f(h2bc(w0.w), c3, o0);
    o1 = fdot2f(h2bc(w1.x), c0, o1);
    o1 = fdot2f(h2bc(w1.y), c1, o1);
    o1 = fdot2f(h2bc(w1.z), c2, o1);
    o1 = fdot2f(h2bc(w1.w), c3, o1);
  }
  out[(size_t)t * EDIM + eo2]     = o0;
  out[(size_t)t * EDIM + eo2 + 1] = o1;
}

// ---------------------------------------------------------------------------
extern "C" void kernel_launch(void* const* d_in, const int* in_sizes, int n_in,
                              void* d_out, int out_size, void* d_ws, size_t ws_size,
                              hipStream_t stream) {
  const float* x    = (const float*)d_in[0];
  const float* wihf = (const float*)d_in[1];
  const float* whhf = (const float*)d_in[2];
  const float* bf   = (const float*)d_in[3];
  const float* wihb = (const float*)d_in[4];
  const float* whhb = (const float*)d_in[5];
  const float* bbv  = (const float*)d_in[6];
  const float* te   = (const float*)d_in[7];
  const float* wq   = (const float*)d_in[8];
  const float* bq   = (const float*)d_in[9];
  const float* wk   = (const float*)d_in[10];
  const float* bk   = (const float*)d_in[11];
  const float* wvv  = (const float*)d_in[12];
  const float* bv   = (const float*)d_in[13];
  const float* wo   = (const float*)d_in[14];
  const float* bo   = (const float*)d_in[15];
  float* out = (float*)d_out;

  char* ws = (char*)d_ws;
  half_t* emb  = (half_t*)(ws + EMB_OFF);
  half_t* q_ws = (half_t*)(ws + Q_OFF);
  half_t* wq16 = (half_t*)(ws + WQ_OFF);
  half_t* wk16 = (half_t*)(ws + WK_OFF);
  half_t* wv16 = (half_t*)(ws + WV_OFF);
  half_t* wo16 = (half_t*)(ws + WO_OFF);
  half_t* te16 = (half_t*)(ws + TE_OFF);

  convert_kernel<<<1040, 256, 0, stream>>>(wq, wk, wvv, wo, te, wq16, wk16, wv16, wo16, te16);

  (void)hipFuncSetAttribute((const void*)lstm_kernel,
                            hipFuncAttributeMaxDynamicSharedMemorySize, LSTM_LDS_BYTES);
  lstm_kernel<<<64, 256, LSTM_LDS_BYTES, stream>>>(x, wihf, whhf, bf, wihb, whhb, bbv, emb);

  qproj_kernel<<<64, 256, 0, stream>>>(emb, wq16, bq, q_ws);

  attn_kernel<<<2048, 256, 0, stream>>>(emb, q_ws, wk16, wv16, wo16, te16, bk, bv, bo, out);
}

// Round 4
// 3628.620 us; speedup vs baseline: 1.9424x; 1.9424x over previous
//
#include <hip/hip_runtime.h>

typedef _Float16 half_t;
typedef _Float16 half2_t __attribute__((ext_vector_type(2)));
typedef _Float16 half4_t __attribute__((ext_vector_type(4)));
typedef _Float16 half8_t __attribute__((ext_vector_type(8)));
typedef float    floatx4 __attribute__((ext_vector_type(4)));

#define T_SEQ 2048
#define EDIM  512

// workspace layout (bytes). total required ~71.4 MB
static constexpr size_t EMB_OFF = 0;                       // 32*2048*512 f16 = 67,108,864
static constexpr size_t Q_OFF   = 67108864;                // 2048*512 f16   =  2,097,152  (x16 aliased here during LSTM)
static constexpr size_t WQ_OFF  = Q_OFF  + 2097152;        // 512*512 f16    =    524,288
static constexpr size_t WK_OFF  = WQ_OFF + 524288;
static constexpr size_t WV_OFF  = WK_OFF + 524288;
static constexpr size_t WO_OFF  = WV_OFF + 524288;
static constexpr size_t TE_OFF  = WO_OFF + 524288;         // 32*512 f16 = 32,768 -> end 71,335,936

__device__ __forceinline__ float fdot2f(half2_t a, half2_t b, float c) {
#if __has_builtin(__builtin_amdgcn_fdot2)
  return __builtin_amdgcn_fdot2(a, b, c, false);
#else
  return c + (float)a[0] * (float)b[0] + (float)a[1] * (float)b[1];
#endif
}
__device__ __forceinline__ half2_t mkh2(float a, float b) {
  half2_t r; r[0] = (half_t)a; r[1] = (half_t)b; return r;
}
__device__ __forceinline__ half2_t h2bc(unsigned u) { return __builtin_bit_cast(half2_t, u); }
__device__ __forceinline__ unsigned h2u(half2_t h)  { return __builtin_bit_cast(unsigned, h); }
__device__ __forceinline__ float sigm(float v)  { return __builtin_amdgcn_rcpf(1.f + __expf(-v)); }
__device__ __forceinline__ float tanhf_(float v){ return __builtin_amdgcn_rcpf(1.f + __expf(-2.f * v)) * 2.f - 1.f; }

// ---------------------------------------------------------------------------
// convert fp32 weights + type_emb + x to f16 in workspace
// elems: 4*262144 (mats) + 16384 (te) + 786432 (x) = 1,851,392 ; /4/256 = 1808 blocks
__global__ void convert_kernel(const float* __restrict__ wq, const float* __restrict__ wk,
                               const float* __restrict__ wvv, const float* __restrict__ wo,
                               const float* __restrict__ te, const float* __restrict__ x,
                               half_t* __restrict__ wq16, half_t* __restrict__ wk16,
                               half_t* __restrict__ wv16, half_t* __restrict__ wo16,
                               half_t* __restrict__ te16, half_t* __restrict__ x16) {
  int i4 = (blockIdx.x * 256 + threadIdx.x) * 4;
  const float* src; half_t* dst; int off;
  if      (i4 < 262144)     { src = wq;  dst = wq16; off = i4; }
  else if (i4 < 2 * 262144) { src = wk;  dst = wk16; off = i4 - 262144; }
  else if (i4 < 3 * 262144) { src = wvv; dst = wv16; off = i4 - 2 * 262144; }
  else if (i4 < 4 * 262144) { src = wo;  dst = wo16; off = i4 - 3 * 262144; }
  else if (i4 < 4 * 262144 + 16384) { src = te; dst = te16; off = i4 - 4 * 262144; }
  else                      { src = x;   dst = x16;  off = i4 - (4 * 262144 + 16384); }
  float4 v = *(const float4*)(src + off);
  half4_t h; h[0] = (half_t)v.x; h[1] = (half_t)v.y; h[2] = (half_t)v.z; h[3] = (half_t)v.w;
  *(half4_t*)(dst + off) = h;
}

// ---------------------------------------------------------------------------
// LSTM: one (branch,dir) chain per block, 512 threads. Thread t -> hidden
// unit j=t>>1, h-half hf=t&1. Each thread: 4 gate rows x 128 h-dims;
// dims [hf*128, hf*128+96) in VGPRs (192 half2-regs), [..+96, ..+128) in LDS.
// Pair partial gate sums combined via shfl_xor(.,1). Input-proj+bias: even
// lanes own gates i,f; odd lanes own gates g,o. One barrier/step.
#define LSTM_LDS_BYTES (16 * 512 * 16 + 2 * 256 * 2)  // wtail 131072 + hbuf 1024

__global__ __launch_bounds__(512, 2)
void lstm_kernel(const half_t* __restrict__ x16,
                 const float* __restrict__ wih_f, const float* __restrict__ whh_f, const float* __restrict__ b_f,
                 const float* __restrict__ wih_b, const float* __restrict__ whh_b, const float* __restrict__ b_b,
                 half_t* __restrict__ emb) {
  extern __shared__ char smem[];
  uint4*  wtail = (uint4*)smem;                    // [4 rows * 4 chunks][512 threads]
  half_t* hbuf  = (half_t*)(smem + 16 * 512 * 16); // [2][256]

  const int bid = blockIdx.x;
  const int n = bid >> 1, dir = bid & 1;
  const int t = threadIdx.x;
  const int j = t >> 1, hf = t & 1;
  const float* wih  = dir ? wih_b : wih_f;
  const float* whh  = dir ? whh_b : whh_f;
  const float* bias = dir ? b_b   : b_f;

  half2_t w[4][48];     // h-dims [hf*128, hf*128+96), 4 gate rows
  half2_t wir[2][6];    // input proj for this thread's 2 owned gate rows
  float   bb0, bb1;

#pragma unroll
  for (int r = 0; r < 4; ++r) {
    const size_t row = (size_t)n * 1024 + r * 256 + j;
    const float4* wp = (const float4*)(whh + row * 256 + hf * 128);
#pragma unroll
    for (int c = 0; c < 24; ++c) {               // dims 0..95 of this half
      float4 w4 = wp[c];
      w[r][c * 2]     = mkh2(w4.x, w4.y);
      w[r][c * 2 + 1] = mkh2(w4.z, w4.w);
    }
#pragma unroll
    for (int c = 0; c < 4; ++c) {                // dims 96..127 of this half
      float4 a = wp[24 + 2 * c], b2 = wp[25 + 2 * c];
      uint4 u;
      u.x = h2u(mkh2(a.x, a.y));   u.y = h2u(mkh2(a.z, a.w));
      u.z = h2u(mkh2(b2.x, b2.y)); u.w = h2u(mkh2(b2.z, b2.w));
      wtail[(r * 4 + c) * 512 + t] = u;
    }
  }
  {
    const int rbase = hf * 2;                    // even: rows 0,1 (i,f); odd: rows 2,3 (g,o)
#pragma unroll
    for (int rr = 0; rr < 2; ++rr) {
      const size_t row = (size_t)n * 1024 + (rbase + rr) * 256 + j;
      const float4* ip = (const float4*)(wih + row * 12);
      float4 a = ip[0], b2 = ip[1], c4 = ip[2];
      wir[rr][0] = mkh2(a.x, a.y);  wir[rr][1] = mkh2(a.z, a.w);
      wir[rr][2] = mkh2(b2.x, b2.y); wir[rr][3] = mkh2(b2.z, b2.w);
      wir[rr][4] = mkh2(c4.x, c4.y); wir[rr][5] = mkh2(c4.z, c4.w);
    }
    bb0 = bias[(size_t)n * 1024 + (rbase + 0) * 256 + j];
    bb1 = bias[(size_t)n * 1024 + (rbase + 1) * 256 + j];
  }
  if (t < 256) hbuf[t] = (half_t)0.f;            // h_{-1} = 0 (buffer 0)
  __syncthreads();

  float cst = 0.f;
  half2_t xh[6];
  {
    const int t0 = dir ? 2047 : 0;
    const uint2* xp = (const uint2*)(x16 + ((size_t)n * T_SEQ + t0) * 12);
    uint2 u0 = xp[0], u1 = xp[1], u2 = xp[2];
    xh[0] = h2bc(u0.x); xh[1] = h2bc(u0.y);
    xh[2] = h2bc(u1.x); xh[3] = h2bc(u1.y);
    xh[4] = h2bc(u2.x); xh[5] = h2bc(u2.y);
  }

#pragma unroll 1
  for (int s = 0; s < T_SEQ; ++s) {
    const int tcur = dir ? (2047 - s) : s;
    int tnext = dir ? (2046 - s) : (s + 1);
    if (s == 2047) tnext = tcur;
    const uint2* xnp = (const uint2*)(x16 + ((size_t)n * T_SEQ + tnext) * 12);
    uint2 u0 = xnp[0], u1 = xnp[1], u2 = xnp[2];

    // input projection + bias for this thread's 2 owned gates
    float p0 = bb0, p1 = bb1;
#pragma unroll
    for (int d = 0; d < 6; ++d) {
      p0 = fdot2f(wir[0][d], xh[d], p0);
      p1 = fdot2f(wir[1][d], xh[d], p1);
    }
    float acc0 = hf ? 0.f : p0;
    float acc1 = hf ? 0.f : p1;
    float acc2 = hf ? p0 : 0.f;
    float acc3 = hf ? p1 : 0.f;

    // recurrent partials over this thread's 128 h-dims
    const uint4* hb = (const uint4*)(hbuf + (s & 1) * 256) + hf * 16;
#pragma unroll
    for (int c = 0; c < 12; ++c) {               // register-weight part (96 dims)
      uint4 hv = hb[c];
      half2_t h0 = h2bc(hv.x), h1 = h2bc(hv.y), h2 = h2bc(hv.z), h3 = h2bc(hv.w);
      acc0 = fdot2f(w[0][4 * c + 0], h0, acc0);
      acc0 = fdot2f(w[0][4 * c + 1], h1, acc0);
      acc0 = fdot2f(w[0][4 * c + 2], h2, acc0);
      acc0 = fdot2f(w[0][4 * c + 3], h3, acc0);
      acc1 = fdot2f(w[1][4 * c + 0], h0, acc1);
      acc1 = fdot2f(w[1][4 * c + 1], h1, acc1);
      acc1 = fdot2f(w[1][4 * c + 2], h2, acc1);
      acc1 = fdot2f(w[1][4 * c + 3], h3, acc1);
      acc2 = fdot2f(w[2][4 * c + 0], h0, acc2);
      acc2 = fdot2f(w[2][4 * c + 1], h1, acc2);
      acc2 = fdot2f(w[2][4 * c + 2], h2, acc2);
      acc2 = fdot2f(w[2][4 * c + 3], h3, acc2);
      acc3 = fdot2f(w[3][4 * c + 0], h0, acc3);
      acc3 = fdot2f(w[3][4 * c + 1], h1, acc3);
      acc3 = fdot2f(w[3][4 * c + 2], h2, acc3);
      acc3 = fdot2f(w[3][4 * c + 3], h3, acc3);
    }
#pragma unroll
    for (int c = 0; c < 4; ++c) {                // LDS-weight part (32 dims)
      uint4 hv = hb[12 + c];
      half2_t h0 = h2bc(hv.x), h1 = h2bc(hv.y), h2 = h2bc(hv.z), h3 = h2bc(hv.w);
      uint4 w0 = wtail[(0 * 4 + c) * 512 + t];
      acc0 = fdot2f(h2bc(w0.x), h0, acc0);
      acc0 = fdot2f(h2bc(w0.y), h1, acc0);
      acc0 = fdot2f(h2bc(w0.z), h2, acc0);
      acc0 = fdot2f(h2bc(w0.w), h3, acc0);
      uint4 w1 = wtail[(1 * 4 + c) * 512 + t];
      acc1 = fdot2f(h2bc(w1.x), h0, acc1);
      acc1 = fdot2f(h2bc(w1.y), h1, acc1);
      acc1 = fdot2f(h2bc(w1.z), h2, acc1);
      acc1 = fdot2f(h2bc(w1.w), h3, acc1);
      uint4 w2 = wtail[(2 * 4 + c) * 512 + t];
      acc2 = fdot2f(h2bc(w2.x), h0, acc2);
      acc2 = fdot2f(h2bc(w2.y), h1, acc2);
      acc2 = fdot2f(h2bc(w2.z), h2, acc2);
      acc2 = fdot2f(h2bc(w2.w), h3, acc2);
      uint4 w3 = wtail[(3 * 4 + c) * 512 + t];
      acc3 = fdot2f(h2bc(w3.x), h0, acc3);
      acc3 = fdot2f(h2bc(w3.y), h1, acc3);
      acc3 = fdot2f(h2bc(w3.z), h2, acc3);
      acc3 = fdot2f(h2bc(w3.w), h3, acc3);
    }

    // combine pair partials (t and t^1 are in the same wave)
    acc0 += __shfl_xor(acc0, 1);
    acc1 += __shfl_xor(acc1, 1);
    acc2 += __shfl_xor(acc2, 1);
    acc3 += __shfl_xor(acc3, 1);

    float si = sigm(acc0), sf = sigm(acc1), gg = tanhf_(acc2), so = sigm(acc3);
    cst = sf * cst + si * gg;
    float h = so * tanhf_(cst);
    if (!hf) {
      half_t hh = (half_t)h;
      hbuf[((s + 1) & 1) * 256 + j] = hh;
      emb[((size_t)n * T_SEQ + tcur) * EDIM + dir * 256 + j] = hh;
    }

    xh[0] = h2bc(u0.x); xh[1] = h2bc(u0.y);
    xh[2] = h2bc(u1.x); xh[3] = h2bc(u1.y);
    xh[4] = h2bc(u2.x); xh[5] = h2bc(u2.y);
    __syncthreads();
  }
}

// ---------------------------------------------------------------------------
// q projection: q[t] = emb[branch0,t] @ wq^T + bq, stored f16. Blocks of 32 t.
__global__ __launch_bounds__(256, 1)
void qproj_kernel(const half_t* __restrict__ emb, const half_t* __restrict__ wq16,
                  const float* __restrict__ bq, half_t* __restrict__ q_ws) {
  const int t0 = blockIdx.x * 32;
  const int tid = threadIdx.x;
  const int lane = tid & 63, wid = tid >> 6;
  const int col = lane & 15, grp = lane >> 4;

  floatx4 acc[2][8];
#pragma unroll
  for (int nt = 0; nt < 8; ++nt) {
    int eo = wid * 128 + nt * 16 + col;
    float b = bq[eo];
#pragma unroll
    for (int mt = 0; mt < 2; ++mt) { acc[mt][nt][0] = b; acc[mt][nt][1] = b; acc[mt][nt][2] = b; acc[mt][nt][3] = b; }
  }
  for (int kc = 0; kc < 16; ++kc) {
    const int e = kc * 32 + grp * 8;
    half8_t a[2];
#pragma unroll
    for (int mt = 0; mt < 2; ++mt) {
      int trow = t0 + mt * 16 + col;
      a[mt] = *(const half8_t*)(emb + (size_t)trow * EDIM + e);   // branch 0
    }
#pragma unroll
    for (int nt = 0; nt < 8; ++nt) {
      int eo = wid * 128 + nt * 16 + col;
      half8_t bf = *(const half8_t*)(wq16 + (size_t)eo * EDIM + e);
#pragma unroll
      for (int mt = 0; mt < 2; ++mt)
        acc[mt][nt] = __builtin_amdgcn_mfma_f32_16x16x32_f16(a[mt], bf, acc[mt][nt], 0, 0, 0);
    }
  }
#pragma unroll
  for (int mt = 0; mt < 2; ++mt)
#pragma unroll
    for (int nt = 0; nt < 8; ++nt)
#pragma unroll
      for (int r = 0; r < 4; ++r) {
        int trow = t0 + mt * 16 + grp * 4 + r;
        int eo = wid * 128 + nt * 16 + col;
        q_ws[(size_t)trow * EDIM + eo] = (half_t)acc[mt][nt][r];
      }
}

// ---------------------------------------------------------------------------
// fused attention per timestep t: K/V GEMM (MFMA, accs stay in regs),
// scores+softmax via shfl, ctx via shfl, out-projection. 2 KB LDS.
__global__ __launch_bounds__(256, 1)
void attn_kernel(const half_t* __restrict__ emb, const half_t* __restrict__ q_ws,
                 const half_t* __restrict__ wk16, const half_t* __restrict__ wv16,
                 const half_t* __restrict__ wo16, const half_t* __restrict__ te16,
                 const float* __restrict__ bk, const float* __restrict__ bv,
                 const float* __restrict__ bo, float* __restrict__ out) {
  __shared__ float  scores_lds[128];
  __shared__ float  w_lds[128];
  __shared__ half_t ctx_lds[512];

  const int t = blockIdx.x;
  const int tid = threadIdx.x;
  const int lane = tid & 63, wid = tid >> 6;   // wid == head
  const int col = lane & 15, grp = lane >> 4;

  // ---- Phase 1: K,V GEMM ----
  floatx4 kacc[2][8], vacc[2][8];
#pragma unroll
  for (int nt = 0; nt < 8; ++nt) {
    int eo = wid * 128 + nt * 16 + col;
    float kb = bk[eo], vb = bv[eo];
#pragma unroll
    for (int mt = 0; mt < 2; ++mt) {
      kacc[mt][nt][0] = kb; kacc[mt][nt][1] = kb; kacc[mt][nt][2] = kb; kacc[mt][nt][3] = kb;
      vacc[mt][nt][0] = vb; vacc[mt][nt][1] = vb; vacc[mt][nt][2] = vb; vacc[mt][nt][3] = vb;
    }
  }
  for (int kc = 0; kc < 16; ++kc) {
    const int e = kc * 32 + grp * 8;
    half8_t av[2], ak[2];
#pragma unroll
    for (int mt = 0; mt < 2; ++mt) {
      int branch = mt * 16 + col;
      av[mt] = *(const half8_t*)(emb + ((size_t)branch * T_SEQ + t) * EDIM + e);
      half8_t te = *(const half8_t*)(te16 + (size_t)branch * EDIM + e);
      ak[mt] = av[mt] + te;
    }
#pragma unroll
    for (int nt = 0; nt < 8; ++nt) {
      int eo = wid * 128 + nt * 16 + col;
      half8_t bkf = *(const half8_t*)(wk16 + (size_t)eo * EDIM + e);
      half8_t bvf = *(const half8_t*)(wv16 + (size_t)eo * EDIM + e);
#pragma unroll
      for (int mt = 0; mt < 2; ++mt) {
        kacc[mt][nt] = __builtin_amdgcn_mfma_f32_16x16x32_f16(ak[mt], bkf, kacc[mt][nt], 0, 0, 0);
        vacc[mt][nt] = __builtin_amdgcn_mfma_f32_16x16x32_f16(av[mt], bvf, vacc[mt][nt], 0, 0, 0);
      }
    }
  }

  // ---- Phase 2: scores + softmax (per wave = per head) ----
  float spart[8];
#pragma unroll
  for (int i = 0; i < 8; ++i) spart[i] = 0.f;
#pragma unroll
  for (int nt = 0; nt < 8; ++nt) {
    int eo = wid * 128 + nt * 16 + col;
    float qf = (float)q_ws[(size_t)t * EDIM + eo];
#pragma unroll
    for (int mt = 0; mt < 2; ++mt)
#pragma unroll
      for (int r = 0; r < 4; ++r)
        spart[mt * 4 + r] += qf * kacc[mt][nt][r];
  }
#pragma unroll
  for (int i = 0; i < 8; ++i) {
    float v = spart[i];
    v += __shfl_xor(v, 1); v += __shfl_xor(v, 2); v += __shfl_xor(v, 4); v += __shfl_xor(v, 8);
    spart[i] = v;
  }
  const float scale = 0.08838834764831845f;  // 1/sqrt(128)
  if (col == 0) {
#pragma unroll
    for (int mt = 0; mt < 2; ++mt)
#pragma unroll
      for (int r = 0; r < 4; ++r)
        scores_lds[wid * 32 + mt * 16 + grp * 4 + r] = spart[mt * 4 + r] * scale;
  }
  float sc = scores_lds[wid * 32 + (lane & 31)];
  float m = sc;
  m = fmaxf(m, __shfl_xor(m, 1));  m = fmaxf(m, __shfl_xor(m, 2));
  m = fmaxf(m, __shfl_xor(m, 4));  m = fmaxf(m, __shfl_xor(m, 8));
  m = fmaxf(m, __shfl_xor(m, 16));
  float ex = __expf(sc - m);
  float sm = ex;
  sm += __shfl_xor(sm, 1); sm += __shfl_xor(sm, 2); sm += __shfl_xor(sm, 4);
  sm += __shfl_xor(sm, 8); sm += __shfl_xor(sm, 16);
  float wn = ex * __builtin_amdgcn_rcpf(sm);
  if (lane < 32) w_lds[wid * 32 + lane] = wn;

  // ---- Phase 3: ctx from vacc (per wave, in-register) ----
  float wb[8];
#pragma unroll
  for (int mt = 0; mt < 2; ++mt)
#pragma unroll
    for (int r = 0; r < 4; ++r)
      wb[mt * 4 + r] = w_lds[wid * 32 + mt * 16 + grp * 4 + r];
#pragma unroll
  for (int nt = 0; nt < 8; ++nt) {
    float cx = 0.f;
#pragma unroll
    for (int mt = 0; mt < 2; ++mt)
#pragma unroll
      for (int r = 0; r < 4; ++r)
        cx += wb[mt * 4 + r] * vacc[mt][nt][r];
    cx += __shfl_xor(cx, 16);
    cx += __shfl_xor(cx, 32);
    float cxh = __shfl_xor(cx, 1);
    if ((lane < 16) && ((lane & 1) == 0))
      *(half2_t*)(ctx_lds + wid * 128 + nt * 16 + lane) = mkh2(cx, cxh);
  }
  __syncthreads();

  // ---- Phase 4: attn output + out-projection ----
  if (tid < 32) {
    float a = 0.25f * (w_lds[tid] + w_lds[32 + tid] + w_lds[64 + tid] + w_lds[96 + tid]);
    out[1048576 + (size_t)t * 32 + tid] = a;
  }
  const int eo2 = tid * 2;
  float o0 = bo[eo2], o1 = bo[eo2 + 1];
  const uint4* cl = (const uint4*)ctx_lds;
  const half_t* wrow0 = wo16 + (size_t)eo2 * EDIM;
  const half_t* wrow1 = wrow0 + EDIM;
#pragma unroll 8
  for (int c = 0; c < 64; ++c) {
    uint4 cv = cl[c];
    uint4 w0 = *(const uint4*)(wrow0 + c * 8);
    uint4 w1 = *(const uint4*)(wrow1 + c * 8);
    half2_t c0 = h2bc(cv.x), c1 = h2bc(cv.y), c2 = h2bc(cv.z), c3 = h2bc(cv.w);
    o0 = fdot2f(h2bc(w0.x), c0, o0);
    o0 = fdot2f(h2bc(w0.y), c1, o0);
    o0 = fdot2f(h2bc(w0.z), c2, o0);
    o0 = fdot2f(h2bc(w0.w), c3, o0);
    o1 = fdot2f(h2bc(w1.x), c0, o1);
    o1 = fdot2f(h2bc(w1.y), c1, o1);
    o1 = fdot2f(h2bc(w1.z), c2, o1);
    o1 = fdot2f(h2bc(w1.w), c3, o1);
  }
  out[(size_t)t * EDIM + eo2]     = o0;
  out[(size_t)t * EDIM + eo2 + 1] = o1;
}

// ---------------------------------------------------------------------------
extern "C" void kernel_launch(void* const* d_in, const int* in_sizes, int n_in,
                              void* d_out, int out_size, void* d_ws, size_t ws_size,
                              hipStream_t stream) {
  const float* x    = (const float*)d_in[0];
  const float* wihf = (const float*)d_in[1];
  const float* whhf = (const float*)d_in[2];
  const float* bf   = (const float*)d_in[3];
  const float* wihb = (const float*)d_in[4];
  const float* whhb = (const float*)d_in[5];
  const float* bbv  = (const float*)d_in[6];
  const float* te   = (const float*)d_in[7];
  const float* wq   = (const float*)d_in[8];
  const float* bq   = (const float*)d_in[9];
  const float* wk   = (const float*)d_in[10];
  const float* bk   = (const float*)d_in[11];
  const float* wvv  = (const float*)d_in[12];
  const float* bv   = (const float*)d_in[13];
  const float* wo   = (const float*)d_in[14];
  const float* bo   = (const float*)d_in[15];
  float* out = (float*)d_out;

  char* ws = (char*)d_ws;
  half_t* emb  = (half_t*)(ws + EMB_OFF);
  half_t* q_ws = (half_t*)(ws + Q_OFF);     // x16 aliased here during LSTM phase
  half_t* x16  = (half_t*)(ws + Q_OFF);
  half_t* wq16 = (half_t*)(ws + WQ_OFF);
  half_t* wk16 = (half_t*)(ws + WK_OFF);
  half_t* wv16 = (half_t*)(ws + WV_OFF);
  half_t* wo16 = (half_t*)(ws + WO_OFF);
  half_t* te16 = (half_t*)(ws + TE_OFF);

  convert_kernel<<<1808, 256, 0, stream>>>(wq, wk, wvv, wo, te, x,
                                           wq16, wk16, wv16, wo16, te16, x16);

  (void)hipFuncSetAttribute((const void*)lstm_kernel,
                            hipFuncAttributeMaxDynamicSharedMemorySize, LSTM_LDS_BYTES);
  lstm_kernel<<<64, 512, LSTM_LDS_BYTES, stream>>>(x16, wihf, whhf, bf, wihb, whhb, bbv, emb);

  qproj_kernel<<<64, 256, 0, stream>>>(emb, wq16, bq, q_ws);

  attn_kernel<<<2048, 256, 0, stream>>>(emb, q_ws, wk16, wv16, wo16, te16, bk, bv, bo, out);
}

// Round 5
// 3626.527 us; speedup vs baseline: 1.9436x; 1.0006x over previous
//
#include <hip/hip_runtime.h>

typedef _Float16 half_t;
typedef _Float16 half2_t __attribute__((ext_vector_type(2)));
typedef _Float16 half4_t __attribute__((ext_vector_type(4)));
typedef _Float16 half8_t __attribute__((ext_vector_type(8)));
typedef float    floatx4 __attribute__((ext_vector_type(4)));

#define T_SEQ 2048
#define EDIM  512

// workspace layout (bytes). total required ~71.4 MB
static constexpr size_t EMB_OFF = 0;                       // 32*2048*512 f16 = 67,108,864
static constexpr size_t Q_OFF   = 67108864;                // 2048*512 f16   =  2,097,152  (x16 aliased here during LSTM)
static constexpr size_t WQ_OFF  = Q_OFF  + 2097152;        // 512*512 f16    =    524,288
static constexpr size_t WK_OFF  = WQ_OFF + 524288;
static constexpr size_t WV_OFF  = WK_OFF + 524288;
static constexpr size_t WO_OFF  = WV_OFF + 524288;
static constexpr size_t TE_OFF  = WO_OFF + 524288;         // 32*512 f16 = 32,768 -> end 71,335,936

__device__ __forceinline__ float fdot2f(half2_t a, half2_t b, float c) {
#if __has_builtin(__builtin_amdgcn_fdot2)
  return __builtin_amdgcn_fdot2(a, b, c, false);
#else
  return c + (float)a[0] * (float)b[0] + (float)a[1] * (float)b[1];
#endif
}
__device__ __forceinline__ half2_t mkh2(float a, float b) {
  half2_t r; r[0] = (half_t)a; r[1] = (half_t)b; return r;
}
__device__ __forceinline__ half2_t h2bc(unsigned u) { return __builtin_bit_cast(half2_t, u); }
__device__ __forceinline__ unsigned h2u(half2_t h)  { return __builtin_bit_cast(unsigned, h); }
__device__ __forceinline__ float sigm(float v)  { return __builtin_amdgcn_rcpf(1.f + __expf(-v)); }
__device__ __forceinline__ float tanhf_(float v){ return __builtin_amdgcn_rcpf(1.f + __expf(-2.f * v)) * 2.f - 1.f; }

// ---------------------------------------------------------------------------
// convert fp32 weights + type_emb + x to f16 in workspace
// elems: 4*262144 (mats) + 16384 (te) + 786432 (x) = 1,851,392 ; /4/256 = 1808 blocks
__global__ void convert_kernel(const float* __restrict__ wq, const float* __restrict__ wk,
                               const float* __restrict__ wvv, const float* __restrict__ wo,
                               const float* __restrict__ te, const float* __restrict__ x,
                               half_t* __restrict__ wq16, half_t* __restrict__ wk16,
                               half_t* __restrict__ wv16, half_t* __restrict__ wo16,
                               half_t* __restrict__ te16, half_t* __restrict__ x16) {
  int i4 = (blockIdx.x * 256 + threadIdx.x) * 4;
  const float* src; half_t* dst; int off;
  if      (i4 < 262144)     { src = wq;  dst = wq16; off = i4; }
  else if (i4 < 2 * 262144) { src = wk;  dst = wk16; off = i4 - 262144; }
  else if (i4 < 3 * 262144) { src = wvv; dst = wv16; off = i4 - 2 * 262144; }
  else if (i4 < 4 * 262144) { src = wo;  dst = wo16; off = i4 - 3 * 262144; }
  else if (i4 < 4 * 262144 + 16384) { src = te; dst = te16; off = i4 - 4 * 262144; }
  else                      { src = x;   dst = x16;  off = i4 - (4 * 262144 + 16384); }
  float4 v = *(const float4*)(src + off);
  half4_t h; h[0] = (half_t)v.x; h[1] = (half_t)v.y; h[2] = (half_t)v.z; h[3] = (half_t)v.w;
  *(half4_t*)(dst + off) = h;
}

// ---------------------------------------------------------------------------
// LSTM: one (branch,dir) chain per block, 512 threads. Thread t -> hidden
// unit j=t>>1, h-half hf=t&1. Each thread: 4 gate rows x 128 h-dims;
// dims [hf*128, hf*128+96) in VGPRs (192 half2-regs), [..+96, ..+128) in LDS.
// waves_per_eu(2,2) pins the VGPR budget at 256 so weights stay in arch VGPRs
// (R4: compiler targeted 128 VGPRs -> AGPR/scratch spill, +190 VALU instr/step).
// hbuf halves padded 16B apart so even/odd broadcast reads hit disjoint banks
// (R4: 6.7e7 conflict cycles from X / X+256B same-bank dual-broadcast).
#define HB_STRIDE 272  // halfs per h buffer: 128 | 8 pad | 128 | 8 pad
#define LSTM_LDS_BYTES (16 * 512 * 16 + 2 * HB_STRIDE * 2)  // 131072 + 1088

__global__ __attribute__((amdgpu_flat_work_group_size(512, 512), amdgpu_waves_per_eu(2, 2)))
void lstm_kernel(const half_t* __restrict__ x16,
                 const float* __restrict__ wih_f, const float* __restrict__ whh_f, const float* __restrict__ b_f,
                 const float* __restrict__ wih_b, const float* __restrict__ whh_b, const float* __restrict__ b_b,
                 half_t* __restrict__ emb) {
  extern __shared__ char smem[];
  uint4*  wtail = (uint4*)smem;                    // [4 rows * 4 chunks][512 threads]
  half_t* hbuf  = (half_t*)(smem + 16 * 512 * 16); // [2][HB_STRIDE]

  const int bid = blockIdx.x;
  const int n = bid >> 1, dir = bid & 1;
  const int t = threadIdx.x;
  const int j = t >> 1, hf = t & 1;
  const float* wih  = dir ? wih_b : wih_f;
  const float* whh  = dir ? whh_b : whh_f;
  const float* bias = dir ? b_b   : b_f;

  half2_t w[4][48];     // h-dims [hf*128, hf*128+96), 4 gate rows
  half2_t wir[2][6];    // input proj for this thread's 2 owned gate rows
  float   bb0, bb1;

#pragma unroll
  for (int r = 0; r < 4; ++r) {
    const size_t row = (size_t)n * 1024 + r * 256 + j;
    const float4* wp = (const float4*)(whh + row * 256 + hf * 128);
#pragma unroll
    for (int c = 0; c < 24; ++c) {               // dims 0..95 of this half
      float4 w4 = wp[c];
      w[r][c * 2]     = mkh2(w4.x, w4.y);
      w[r][c * 2 + 1] = mkh2(w4.z, w4.w);
    }
#pragma unroll
    for (int c = 0; c < 4; ++c) {                // dims 96..127 of this half
      float4 a = wp[24 + 2 * c], b2 = wp[25 + 2 * c];
      uint4 u;
      u.x = h2u(mkh2(a.x, a.y));   u.y = h2u(mkh2(a.z, a.w));
      u.z = h2u(mkh2(b2.x, b2.y)); u.w = h2u(mkh2(b2.z, b2.w));
      wtail[(r * 4 + c) * 512 + t] = u;
    }
  }
  {
    const int rbase = hf * 2;                    // even: rows 0,1 (i,f); odd: rows 2,3 (g,o)
#pragma unroll
    for (int rr = 0; rr < 2; ++rr) {
      const size_t row = (size_t)n * 1024 + (rbase + rr) * 256 + j;
      const float4* ip = (const float4*)(wih + row * 12);
      float4 a = ip[0], b2 = ip[1], c4 = ip[2];
      wir[rr][0] = mkh2(a.x, a.y);  wir[rr][1] = mkh2(a.z, a.w);
      wir[rr][2] = mkh2(b2.x, b2.y); wir[rr][3] = mkh2(b2.z, b2.w);
      wir[rr][4] = mkh2(c4.x, c4.y); wir[rr][5] = mkh2(c4.z, c4.w);
    }
    bb0 = bias[(size_t)n * 1024 + (rbase + 0) * 256 + j];
    bb1 = bias[(size_t)n * 1024 + (rbase + 1) * 256 + j];
  }
  if (t < 2 * HB_STRIDE) hbuf[t] = (half_t)0.f;  // h_{-1} = 0 (covers pads too)
  __syncthreads();

  float cst = 0.f;
  half2_t xh[6];
  {
    const int t0 = dir ? 2047 : 0;
    const uint2* xp = (const uint2*)(x16 + ((size_t)n * T_SEQ + t0) * 12);
    uint2 u0 = xp[0], u1 = xp[1], u2 = xp[2];
    xh[0] = h2bc(u0.x); xh[1] = h2bc(u0.y);
    xh[2] = h2bc(u1.x); xh[3] = h2bc(u1.y);
    xh[4] = h2bc(u2.x); xh[5] = h2bc(u2.y);
  }

#pragma unroll 1
  for (int s = 0; s < T_SEQ; ++s) {
    const int tcur = dir ? (2047 - s) : s;
    int tnext = dir ? (2046 - s) : (s + 1);
    if (s == 2047) tnext = tcur;

    // input projection + bias for this thread's 2 owned gates (uses current xh)
    float p0 = bb0, p1 = bb1;
#pragma unroll
    for (int d = 0; d < 6; ++d) {
      p0 = fdot2f(wir[0][d], xh[d], p0);
      p1 = fdot2f(wir[1][d], xh[d], p1);
    }

    // prefetch next x into xh now; latency hides under the recurrent loops
    {
      const uint2* xnp = (const uint2*)(x16 + ((size_t)n * T_SEQ + tnext) * 12);
      uint2 u0 = xnp[0], u1 = xnp[1], u2 = xnp[2];
      xh[0] = h2bc(u0.x); xh[1] = h2bc(u0.y);
      xh[2] = h2bc(u1.x); xh[3] = h2bc(u1.y);
      xh[4] = h2bc(u2.x); xh[5] = h2bc(u2.y);
    }

    float acc0 = hf ? 0.f : p0;
    float acc1 = hf ? 0.f : p1;
    float acc2 = hf ? p0 : 0.f;
    float acc3 = hf ? p1 : 0.f;

    // recurrent partials over this thread's 128 h-dims
    // even lanes read bytes [0,256) of the buffer, odd lanes [272,528) -> disjoint banks
    const uint4* hb = (const uint4*)(hbuf + (s & 1) * HB_STRIDE) + hf * 17;
#pragma unroll
    for (int c = 0; c < 12; ++c) {               // register-weight part (96 dims)
      uint4 hv = hb[c];
      half2_t h0 = h2bc(hv.x), h1 = h2bc(hv.y), h2 = h2bc(hv.z), h3 = h2bc(hv.w);
      acc0 = fdot2f(w[0][4 * c + 0], h0, acc0);
      acc0 = fdot2f(w[0][4 * c + 1], h1, acc0);
      acc0 = fdot2f(w[0][4 * c + 2], h2, acc0);
      acc0 = fdot2f(w[0][4 * c + 3], h3, acc0);
      acc1 = fdot2f(w[1][4 * c + 0], h0, acc1);
      acc1 = fdot2f(w[1][4 * c + 1], h1, acc1);
      acc1 = fdot2f(w[1][4 * c + 2], h2, acc1);
      acc1 = fdot2f(w[1][4 * c + 3], h3, acc1);
      acc2 = fdot2f(w[2][4 * c + 0], h0, acc2);
      acc2 = fdot2f(w[2][4 * c + 1], h1, acc2);
      acc2 = fdot2f(w[2][4 * c + 2], h2, acc2);
      acc2 = fdot2f(w[2][4 * c + 3], h3, acc2);
      acc3 = fdot2f(w[3][4 * c + 0], h0, acc3);
      acc3 = fdot2f(w[3][4 * c + 1], h1, acc3);
      acc3 = fdot2f(w[3][4 * c + 2], h2, acc3);
      acc3 = fdot2f(w[3][4 * c + 3], h3, acc3);
    }
#pragma unroll
    for (int c = 0; c < 4; ++c) {                // LDS-weight part (32 dims)
      uint4 hv = hb[12 + c];
      half2_t h0 = h2bc(hv.x), h1 = h2bc(hv.y), h2 = h2bc(hv.z), h3 = h2bc(hv.w);
      uint4 w0 = wtail[(0 * 4 + c) * 512 + t];
      acc0 = fdot2f(h2bc(w0.x), h0, acc0);
      acc0 = fdot2f(h2bc(w0.y), h1, acc0);
      acc0 = fdot2f(h2bc(w0.z), h2, acc0);
      acc0 = fdot2f(h2bc(w0.w), h3, acc0);
      uint4 w1 = wtail[(1 * 4 + c) * 512 + t];
      acc1 = fdot2f(h2bc(w1.x), h0, acc1);
      acc1 = fdot2f(h2bc(w1.y), h1, acc1);
      acc1 = fdot2f(h2bc(w1.z), h2, acc1);
      acc1 = fdot2f(h2bc(w1.w), h3, acc1);
      uint4 w2 = wtail[(2 * 4 + c) * 512 + t];
      acc2 = fdot2f(h2bc(w2.x), h0, acc2);
      acc2 = fdot2f(h2bc(w2.y), h1, acc2);
      acc2 = fdot2f(h2bc(w2.z), h2, acc2);
      acc2 = fdot2f(h2bc(w2.w), h3, acc2);
      uint4 w3 = wtail[(3 * 4 + c) * 512 + t];
      acc3 = fdot2f(h2bc(w3.x), h0, acc3);
      acc3 = fdot2f(h2bc(w3.y), h1, acc3);
      acc3 = fdot2f(h2bc(w3.z), h2, acc3);
      acc3 = fdot2f(h2bc(w3.w), h3, acc3);
    }

    // combine pair partials (t and t^1 are in the same wave)
    acc0 += __shfl_xor(acc0, 1);
    acc1 += __shfl_xor(acc1, 1);
    acc2 += __shfl_xor(acc2, 1);
    acc3 += __shfl_xor(acc3, 1);

    float si = sigm(acc0), sf = sigm(acc1), gg = tanhf_(acc2), so = sigm(acc3);
    cst = sf * cst + si * gg;
    float h = so * tanhf_(cst);
    if (!hf) {
      half_t hh = (half_t)h;
      const int pos = j + ((j >> 7) << 3);       // skip 8-half pad between halves
      hbuf[((s + 1) & 1) * HB_STRIDE + pos] = hh;
      emb[((size_t)n * T_SEQ + tcur) * EDIM + dir * 256 + j] = hh;
    }
    __syncthreads();
  }
}

// ---------------------------------------------------------------------------
// q projection: q[t] = emb[branch0,t] @ wq^T + bq, stored f16. Blocks of 32 t.
__global__ __launch_bounds__(256, 1)
void qproj_kernel(const half_t* __restrict__ emb, const half_t* __restrict__ wq16,
                  const float* __restrict__ bq, half_t* __restrict__ q_ws) {
  const int t0 = blockIdx.x * 32;
  const int tid = threadIdx.x;
  const int lane = tid & 63, wid = tid >> 6;
  const int col = lane & 15, grp = lane >> 4;

  floatx4 acc[2][8];
#pragma unroll
  for (int nt = 0; nt < 8; ++nt) {
    int eo = wid * 128 + nt * 16 + col;
    float b = bq[eo];
#pragma unroll
    for (int mt = 0; mt < 2; ++mt) { acc[mt][nt][0] = b; acc[mt][nt][1] = b; acc[mt][nt][2] = b; acc[mt][nt][3] = b; }
  }
  for (int kc = 0; kc < 16; ++kc) {
    const int e = kc * 32 + grp * 8;
    half8_t a[2];
#pragma unroll
    for (int mt = 0; mt < 2; ++mt) {
      int trow = t0 + mt * 16 + col;
      a[mt] = *(const half8_t*)(emb + (size_t)trow * EDIM + e);   // branch 0
    }
#pragma unroll
    for (int nt = 0; nt < 8; ++nt) {
      int eo = wid * 128 + nt * 16 + col;
      half8_t bf = *(const half8_t*)(wq16 + (size_t)eo * EDIM + e);
#pragma unroll
      for (int mt = 0; mt < 2; ++mt)
        acc[mt][nt] = __builtin_amdgcn_mfma_f32_16x16x32_f16(a[mt], bf, acc[mt][nt], 0, 0, 0);
    }
  }
#pragma unroll
  for (int mt = 0; mt < 2; ++mt)
#pragma unroll
    for (int nt = 0; nt < 8; ++nt)
#pragma unroll
      for (int r = 0; r < 4; ++r) {
        int trow = t0 + mt * 16 + grp * 4 + r;
        int eo = wid * 128 + nt * 16 + col;
        q_ws[(size_t)trow * EDIM + eo] = (half_t)acc[mt][nt][r];
      }
}

// ---------------------------------------------------------------------------
// fused attention per timestep t: K/V GEMM (MFMA, accs stay in regs),
// scores+softmax via shfl, ctx via shfl, out-projection. 2 KB LDS.
__global__ __launch_bounds__(256, 1)
void attn_kernel(const half_t* __restrict__ emb, const half_t* __restrict__ q_ws,
                 const half_t* __restrict__ wk16, const half_t* __restrict__ wv16,
                 const half_t* __restrict__ wo16, const half_t* __restrict__ te16,
                 const float* __restrict__ bk, const float* __restrict__ bv,
                 const float* __restrict__ bo, float* __restrict__ out) {
  __shared__ float  scores_lds[128];
  __shared__ float  w_lds[128];
  __shared__ half_t ctx_lds[512];

  const int t = blockIdx.x;
  const int tid = threadIdx.x;
  const int lane = tid & 63, wid = tid >> 6;   // wid == head
  const int col = lane & 15, grp = lane >> 4;

  // ---- Phase 1: K,V GEMM ----
  floatx4 kacc[2][8], vacc[2][8];
#pragma unroll
  for (int nt = 0; nt < 8; ++nt) {
    int eo = wid * 128 + nt * 16 + col;
    float kb = bk[eo], vb = bv[eo];
#pragma unroll
    for (int mt = 0; mt < 2; ++mt) {
      kacc[mt][nt][0] = kb; kacc[mt][nt][1] = kb; kacc[mt][nt][2] = kb; kacc[mt][nt][3] = kb;
      vacc[mt][nt][0] = vb; vacc[mt][nt][1] = vb; vacc[mt][nt][2] = vb; vacc[mt][nt][3] = vb;
    }
  }
  for (int kc = 0; kc < 16; ++kc) {
    const int e = kc * 32 + grp * 8;
    half8_t av[2], ak[2];
#pragma unroll
    for (int mt = 0; mt < 2; ++mt) {
      int branch = mt * 16 + col;
      av[mt] = *(const half8_t*)(emb + ((size_t)branch * T_SEQ + t) * EDIM + e);
      half8_t te = *(const half8_t*)(te16 + (size_t)branch * EDIM + e);
      ak[mt] = av[mt] + te;
    }
#pragma unroll
    for (int nt = 0; nt < 8; ++nt) {
      int eo = wid * 128 + nt * 16 + col;
      half8_t bkf = *(const half8_t*)(wk16 + (size_t)eo * EDIM + e);
      half8_t bvf = *(const half8_t*)(wv16 + (size_t)eo * EDIM + e);
#pragma unroll
      for (int mt = 0; mt < 2; ++mt) {
        kacc[mt][nt] = __builtin_amdgcn_mfma_f32_16x16x32_f16(ak[mt], bkf, kacc[mt][nt], 0, 0, 0);
        vacc[mt][nt] = __builtin_amdgcn_mfma_f32_16x16x32_f16(av[mt], bvf, vacc[mt][nt], 0, 0, 0);
      }
    }
  }

  // ---- Phase 2: scores + softmax (per wave = per head) ----
  float spart[8];
#pragma unroll
  for (int i = 0; i < 8; ++i) spart[i] = 0.f;
#pragma unroll
  for (int nt = 0; nt < 8; ++nt) {
    int eo = wid * 128 + nt * 16 + col;
    float qf = (float)q_ws[(size_t)t * EDIM + eo];
#pragma unroll
    for (int mt = 0; mt < 2; ++mt)
#pragma unroll
      for (int r = 0; r < 4; ++r)
        spart[mt * 4 + r] += qf * kacc[mt][nt][r];
  }
#pragma unroll
  for (int i = 0; i < 8; ++i) {
    float v = spart[i];
    v += __shfl_xor(v, 1); v += __shfl_xor(v, 2); v += __shfl_xor(v, 4); v += __shfl_xor(v, 8);
    spart[i] = v;
  }
  const float scale = 0.08838834764831845f;  // 1/sqrt(128)
  if (col == 0) {
#pragma unroll
    for (int mt = 0; mt < 2; ++mt)
#pragma unroll
      for (int r = 0; r < 4; ++r)
        scores_lds[wid * 32 + mt * 16 + grp * 4 + r] = spart[mt * 4 + r] * scale;
  }
  float sc = scores_lds[wid * 32 + (lane & 31)];
  float m = sc;
  m = fmaxf(m, __shfl_xor(m, 1));  m = fmaxf(m, __shfl_xor(m, 2));
  m = fmaxf(m, __shfl_xor(m, 4));  m = fmaxf(m, __shfl_xor(m, 8));
  m = fmaxf(m, __shfl_xor(m, 16));
  float ex = __expf(sc - m);
  float sm = ex;
  sm += __shfl_xor(sm, 1); sm += __shfl_xor(sm, 2); sm += __shfl_xor(sm, 4);
  sm += __shfl_xor(sm, 8); sm += __shfl_xor(sm, 16);
  float wn = ex * __builtin_amdgcn_rcpf(sm);
  if (lane < 32) w_lds[wid * 32 + lane] = wn;

  // ---- Phase 3: ctx from vacc (per wave, in-register) ----
  float wb[8];
#pragma unroll
  for (int mt = 0; mt < 2; ++mt)
#pragma unroll
    for (int r = 0; r < 4; ++r)
      wb[mt * 4 + r] = w_lds[wid * 32 + mt * 16 + grp * 4 + r];
#pragma unroll
  for (int nt = 0; nt < 8; ++nt) {
    float cx = 0.f;
#pragma unroll
    for (int mt = 0; mt < 2; ++mt)
#pragma unroll
      for (int r = 0; r < 4; ++r)
        cx += wb[mt * 4 + r] * vacc[mt][nt][r];
    cx += __shfl_xor(cx, 16);
    cx += __shfl_xor(cx, 32);
    float cxh = __shfl_xor(cx, 1);
    if ((lane < 16) && ((lane & 1) == 0))
      *(half2_t*)(ctx_lds + wid * 128 + nt * 16 + lane) = mkh2(cx, cxh);
  }
  __syncthreads();

  // ---- Phase 4: attn output + out-projection ----
  if (tid < 32) {
    float a = 0.25f * (w_lds[tid] + w_lds[32 + tid] + w_lds[64 + tid] + w_lds[96 + tid]);
    out[1048576 + (size_t)t * 32 + tid] = a;
  }
  const int eo2 = tid * 2;
  float o0 = bo[eo2], o1 = bo[eo2 + 1];
  const uint4* cl = (const uint4*)ctx_lds;
  const half_t* wrow0 = wo16 + (size_t)eo2 * EDIM;
  const half_t* wrow1 = wrow0 + EDIM;
#pragma unroll 8
  for (int c = 0; c < 64; ++c) {
    uint4 cv = cl[c];
    uint4 w0 = *(const uint4*)(wrow0 + c * 8);
    uint4 w1 = *(const uint4*)(wrow1 + c * 8);
    half2_t c0 = h2bc(cv.x), c1 = h2bc(cv.y), c2 = h2bc(cv.z), c3 = h2bc(cv.w);
    o0 = fdot2f(h2bc(w0.x), c0, o0);
    o0 = fdot2f(h2bc(w0.y), c1, o0);
    o0 = fdot2f(h2bc(w0.z), c2, o0);
    o0 = fdot2f(h2bc(w0.w), c3, o0);
    o1 = fdot2f(h2bc(w1.x), c0, o1);
    o1 = fdot2f(h2bc(w1.y), c1, o1);
    o1 = fdot2f(h2bc(w1.z), c2, o1);
    o1 = fdot2f(h2bc(w1.w), c3, o1);
  }
  out[(size_t)t * EDIM + eo2]     = o0;
  out[(size_t)t * EDIM + eo2 + 1] = o1;
}

// ---------------------------------------------------------------------------
extern "C" void kernel_launch(void* const* d_in, const int* in_sizes, int n_in,
                              void* d_out, int out_size, void* d_ws, size_t ws_size,
                              hipStream_t stream) {
  const float* x    = (const float*)d_in[0];
  const float* wihf = (const float*)d_in[1];
  const float* whhf = (const float*)d_in[2];
  const float* bf   = (const float*)d_in[3];
  const float* wihb = (const float*)d_in[4];
  const float* whhb = (const float*)d_in[5];
  const float* bbv  = (const float*)d_in[6];
  const float* te   = (const float*)d_in[7];
  const float* wq   = (const float*)d_in[8];
  const float* bq   = (const float*)d_in[9];
  const float* wk   = (const float*)d_in[10];
  const float* bk   = (const float*)d_in[11];
  const float* wvv  = (const float*)d_in[12];
  const float* bv   = (const float*)d_in[13];
  const float* wo   = (const float*)d_in[14];
  const float* bo   = (const float*)d_in[15];
  float* out = (float*)d_out;

  char* ws = (char*)d_ws;
  half_t* emb  = (half_t*)(ws + EMB_OFF);
  half_t* q_ws = (half_t*)(ws + Q_OFF);     // x16 aliased here during LSTM phase
  half_t* x16  = (half_t*)(ws + Q_OFF);
  half_t* wq16 = (half_t*)(ws + WQ_OFF);
  half_t* wk16 = (half_t*)(ws + WK_OFF);
  half_t* wv16 = (half_t*)(ws + WV_OFF);
  half_t* wo16 = (half_t*)(ws + WO_OFF);
  half_t* te16 = (half_t*)(ws + TE_OFF);

  convert_kernel<<<1808, 256, 0, stream>>>(wq, wk, wvv, wo, te, x,
                                           wq16, wk16, wv16, wo16, te16, x16);

  (void)hipFuncSetAttribute((const void*)lstm_kernel,
                            hipFuncAttributeMaxDynamicSharedMemorySize, LSTM_LDS_BYTES);
  lstm_kernel<<<64, 512, LSTM_LDS_BYTES, stream>>>(x16, wihf, whhf, bf, wihb, whhb, bbv, emb);

  qproj_kernel<<<64, 256, 0, stream>>>(emb, wq16, bq, q_ws);

  attn_kernel<<<2048, 256, 0, stream>>>(emb, q_ws, wk16, wv16, wo16, te16, bk, bv, bo, out);
}